// Round 19
// baseline (346.892 us; speedup 1.0000x reference)
//
#include <hip/hip_runtime.h>

#define H_DIM 1024
#define NHEADS 16
#define HD 64
#define SEQ 1024
#define BATCH 8
#define ROWS (BATCH*SEQ)   // 8192
#define MLPD 4096

typedef __bf16 bf16x8 __attribute__((ext_vector_type(8)));
typedef float f32x4 __attribute__((ext_vector_type(4)));

__device__ __forceinline__ unsigned short f2bf(float f) {
    unsigned u = __float_as_uint(f);
    unsigned r = u + 0x7FFFu + ((u >> 16) & 1u);   // RNE
    return (unsigned short)(r >> 16);
}

// ------- fused weight transpose: all 6 weights fp32(K,N) -> bf16(N,K) -------
__global__ void transpose_all(const float* __restrict__ Wq, const float* __restrict__ Wk,
                              const float* __restrict__ Wv, const float* __restrict__ Wo,
                              const float* __restrict__ W1, const float* __restrict__ W2,
                              unsigned short* __restrict__ WqT, unsigned short* __restrict__ WkT,
                              unsigned short* __restrict__ WvT, unsigned short* __restrict__ WoT,
                              unsigned short* __restrict__ W1T, unsigned short* __restrict__ W2T)
{
    __shared__ float tile[32][33];
    const int id = blockIdx.x;
    const float* in; unsigned short* outp; int K, N, t;
    if (id < 4096) {
        const int wsel = id >> 10; t = id & 1023;
        in   = (wsel == 0) ? Wq  : (wsel == 1) ? Wk  : (wsel == 2) ? Wv  : Wo;
        outp = (wsel == 0) ? WqT : (wsel == 1) ? WkT : (wsel == 2) ? WvT : WoT;
        K = 1024; N = 1024;
    } else if (id < 8192) {
        t = id - 4096; in = W1; outp = W1T; K = 1024; N = 4096;
    } else {
        t = id - 8192; in = W2; outp = W2T; K = 4096; N = 1024;
    }
    const int ntx = N >> 5;
    const int n0 = (t % ntx) * 32, k0 = (t / ntx) * 32;
    const int tx = threadIdx.x, ty = threadIdx.y;      // (32,8)
    #pragma unroll
    for (int i = ty; i < 32; i += 8)
        tile[i][tx] = in[(size_t)(k0 + i) * N + n0 + tx];
    __syncthreads();
    #pragma unroll
    for (int i = ty; i < 32; i += 8)
        outp[(size_t)(n0 + i) * K + k0 + tx] = f2bf(tile[tx][i]);
}

// ---- per-head bf16 transpose with kv-permuted columns (R6-validated) ----
__global__ void transpose_v(const unsigned short* __restrict__ in,
                            unsigned short* __restrict__ out)
{
    __shared__ unsigned short tile[32][33];
    const size_t base = (size_t)blockIdx.z * (SEQ * HD);
    const int d0 = blockIdx.x * 32, s0 = blockIdx.y * 32;
    const int tx = threadIdx.x, ty = threadIdx.y;      // (32,8)
    #pragma unroll
    for (int i = ty; i < 32; i += 8)
        tile[i][tx] = in[base + (size_t)(s0 + i) * HD + d0 + tx];
    __syncthreads();
    const int fx = ((tx & 12) << 1) | ((tx & 16) >> 2) | (tx & 3);   // kv -> kv'
    #pragma unroll
    for (int i = ty; i < 32; i += 8)
        out[base + (size_t)(d0 + i) * SEQ + s0 + fx] = tile[tx][i];
}

// ---------------- layernorm fp32 -> bf16, one block per row ----------------
__global__ __launch_bounds__(256) void ln_kernel(const float* __restrict__ x,
    const float* __restrict__ g, const float* __restrict__ b,
    unsigned short* __restrict__ out)
{
    __shared__ float red[4];
    const int row = blockIdx.x;
    const int tid = threadIdx.x;
    const float4 v = *(const float4*)(x + (size_t)row * H_DIM + tid * 4);
    float s = v.x + v.y + v.z + v.w;
    #pragma unroll
    for (int off = 32; off >= 1; off >>= 1) s += __shfl_xor(s, off);
    if ((tid & 63) == 0) red[tid >> 6] = s;
    __syncthreads();
    const float mu = (red[0] + red[1] + red[2] + red[3]) * (1.0f / H_DIM);
    __syncthreads();
    const float dx = v.x - mu, dy = v.y - mu, dz = v.z - mu, dw = v.w - mu;
    float q = dx * dx + dy * dy + dz * dz + dw * dw;
    #pragma unroll
    for (int off = 32; off >= 1; off >>= 1) q += __shfl_xor(q, off);
    if ((tid & 63) == 0) red[tid >> 6] = q;
    __syncthreads();
    const float var = (red[0] + red[1] + red[2] + red[3]) * (1.0f / H_DIM);
    const float rstd = rsqrtf(var + 1e-6f);
    const float4 gv = *(const float4*)(g + tid * 4);
    const float4 bv = *(const float4*)(b + tid * 4);
    ushort4 o;
    o.x = f2bf(dx * rstd * gv.x + bv.x);
    o.y = f2bf(dy * rstd * gv.y + bv.y);
    o.z = f2bf(dz * rstd * gv.z + bv.z);
    o.w = f2bf(dw * rstd * gv.w + bv.w);
    *(ushort4*)(out + (size_t)row * H_DIM + tid * 4) = o;
}

// ---------------- bf16 GEMM: 128x128, BK=128, 4 waves, single-buffer --------
// MODE 2: f32 out = resid + C
template<int MODE>
__global__ __launch_bounds__(256) void gemm_dp(
    const unsigned short* __restrict__ A, const unsigned short* __restrict__ Bt,
    const float* __restrict__ bias0, const float* __restrict__ bias1,
    const float* __restrict__ bias2, const float* resid,
    float* outF, unsigned short* __restrict__ outH,
    int N, int K, int gn)
{
    __shared__ __align__(16) unsigned short As[128 * 128];   // 32 KB
    __shared__ __align__(16) unsigned short Bs[128 * 128];   // 32 KB

    const int tid = threadIdx.x, lane = tid & 63;
    const int w = tid >> 6;
    const int wm = w >> 1, wn = w & 1;  // 2x2 wave grid, 64x64 per wave

    const int nwg = gridDim.x;
    const int swzb = (blockIdx.x & 7) * (nwg >> 3) + (blockIdx.x >> 3);
    const int bm = swzb / gn, bn = swzb % gn;

    const int srow = tid >> 4;                        // 0..15 (row within round)
    const int sc = (tid & 15) ^ (srow & 7);           // pre-swizzled global chunk
    const unsigned short* Abase = A  + (size_t)(bm * 128) * K;
    const unsigned short* Bbase = Bt + (size_t)(bn * 128) * K;

    auto stage = [&](int kt) {
        const size_t kofs = (size_t)kt * 128 + sc * 8;
        #pragma unroll
        for (int q = 0; q < 8; ++q)
            __builtin_amdgcn_global_load_lds(
                (__attribute__((address_space(1))) void*)(Abase + (size_t)(q * 16 + srow) * K + kofs),
                (__attribute__((address_space(3))) void*)(&As[q * 2048 + tid * 8]), 16, 0, 0);
        #pragma unroll
        for (int q = 0; q < 8; ++q)
            __builtin_amdgcn_global_load_lds(
                (__attribute__((address_space(1))) void*)(Bbase + (size_t)(q * 16 + srow) * K + kofs),
                (__attribute__((address_space(3))) void*)(&Bs[q * 2048 + tid * 8]), 16, 0, 0);
    };

    const int lr = lane & 15, hk = lane >> 4, sx = lr & 7;
    const int arow = (wm * 64 + lr) * 128;
    const int brow = (wn * 64 + lr) * 128;

    f32x4 acc[4][4] = {};
    const int nkt = K >> 7;

    for (int t = 0; t < nkt; ++t) {
        stage(t);
        __syncthreads();                 // drains vmcnt(0): stage(t) landed

        const unsigned short* Ab = &As[arow];
        const unsigned short* Bb = &Bs[brow];

        #pragma unroll
        for (int ks = 0; ks < 4; ++ks) {
            const int px = ((ks * 4 + hk) ^ sx) * 8;
            bf16x8 a[4], b[4];
            #pragma unroll
            for (int i = 0; i < 4; ++i) { b[i] = *(const bf16x8*)(Bb + i * 2048 + px);
                                          a[i] = *(const bf16x8*)(Ab + i * 2048 + px); }
            __builtin_amdgcn_s_setprio(1);
            #pragma unroll
            for (int mi = 0; mi < 4; ++mi)
                #pragma unroll
                for (int ni = 0; ni < 4; ++ni)
                    acc[mi][ni] = __builtin_amdgcn_mfma_f32_16x16x32_bf16(a[mi], b[ni], acc[mi][ni], 0, 0, 0);
            __builtin_amdgcn_s_setprio(0);
        }
        __syncthreads();                 // all reads done before next overwrite
    }

    #pragma unroll
    for (int mi = 0; mi < 4; ++mi) {
        #pragma unroll
        for (int ni = 0; ni < 4; ++ni) {
            const int gcol = bn * 128 + wn * 64 + ni * 16 + lr;
            #pragma unroll
            for (int r = 0; r < 4; ++r) {
                const int grow = bm * 128 + wm * 64 + mi * 16 + hk * 4 + r;
                if (MODE == 2) {
                    const float v = acc[mi][ni][r] + bias0[gcol];
                    const size_t idx = (size_t)grow * N + gcol;
                    outF[idx] = resid[idx] + v;
                }
            }
        }
    }
}

// ---------------- 4-slot K-phased GEMM (R13 phase body + 3-phase lead) -------
// BM=256, BN=256, BK=32 per slot. 8 waves (2M x 4N), per-wave 128x64 (MR=8).
// LDS: 4 slots x (A 16KB + B 16KB) = 128 KB. Phase t: {12 ds_read slot t&3
// [certified] -> stage tile t+3 (4 loads) -> vmcnt(8) [t+1 landed; t+2,t+3 in
// flight] -> ONE barrier -> setprio + 32 MFMA}. 3-phase staging lead (~900cy).
// W-A-R: slot of tile t-1 is overwritten by stage(t+3) issued after
// barrier(t-1+1); all waves' reads of t-1 were lgkm-consumed by MFMA(t-1)
// before they reached that barrier. Swizzle: phys chunk = c ^ ((row>>1)&3)
// within 32-elem rows, source pre-swizzled (R12/R13-validated).
// MODE 0: fused QKV scatter   MODE 3: gelu
template<int MODE>
__global__ __launch_bounds__(512) void gemm_kp4(
    const unsigned short* __restrict__ A, const unsigned short* __restrict__ Bt,
    const float* __restrict__ bias0, const float* __restrict__ bias1,
    const float* __restrict__ bias2,
    unsigned short* __restrict__ outH, int N, int K, int gn)
{
    __shared__ __align__(16) unsigned short As[4][8192];   // 64 KB
    __shared__ __align__(16) unsigned short Bs[4][8192];   // 64 KB

    const int tid = threadIdx.x, lane = tid & 63;
    const int w = tid >> 6;
    const int wm = w >> 2, wn = w & 3;            // 2M x 4N; per-wave 128x64

    const int nwg = gridDim.x;
    const int swzb = (blockIdx.x & 7) * (nwg >> 3) + (blockIdx.x >> 3);
    const int bm = swzb / gn, bn = swzb % gn;

    const unsigned short* Abase = A  + (size_t)(bm * 256) * K;
    const unsigned short* Bbase = Bt + (size_t)(bn * 256) * K;

    // staging map (K-invariant): slot j*512+tid -> row, pre-swizzled src chunk
    int srow[2], soff[2];
    #pragma unroll
    for (int j = 0; j < 2; ++j) {
        const int slot = j * 512 + tid;
        srow[j] = slot >> 2;
        soff[j] = ((slot & 3) ^ ((srow[j] >> 1) & 3)) * 8;
    }

    // stage one BK=32 tile (A+B, 4 loads/thread) into ring slot sl
    auto stage = [&](int sl, int kt) {
        #pragma unroll
        for (int j = 0; j < 2; ++j) {
            const size_t off = (size_t)srow[j] * K + (size_t)kt * 32 + soff[j];
            __builtin_amdgcn_global_load_lds(
                (__attribute__((address_space(1))) void*)(Abase + off),
                (__attribute__((address_space(3))) void*)(&As[sl][(j * 512 + tid) * 8]), 16, 0, 0);
            __builtin_amdgcn_global_load_lds(
                (__attribute__((address_space(1))) void*)(Bbase + off),
                (__attribute__((address_space(3))) void*)(&Bs[sl][(j * 512 + tid) * 8]), 16, 0, 0);
        }
    };

    const int lr = lane & 15, hk = lane >> 4;
    int aoff[8], boff[4];
    #pragma unroll
    for (int mf = 0; mf < 8; ++mf) {
        const int R = wm * 128 + mf * 16 + lr;
        aoff[mf] = R * 32 + ((hk ^ ((R >> 1) & 3)) * 8);
    }
    #pragma unroll
    for (int nf = 0; nf < 4; ++nf) {
        const int R = wn * 64 + nf * 16 + lr;
        boff[nf] = R * 32 + ((hk ^ ((R >> 1) & 3)) * 8);
    }

    f32x4 acc[8][4] = {};
    const int nkt = K >> 5;

    // prologue: 3-deep ring fill; certify tile 0 (tiles 1,2 in flight)
    stage(0, 0); stage(1, 1); stage(2, 2);
    asm volatile("s_waitcnt vmcnt(8)" ::: "memory");
    __builtin_amdgcn_s_barrier();
    asm volatile("" ::: "memory");

    for (int t = 0; t < nkt; ++t) {
        const int sl = t & 3;
        // 1. fragment reads for tile t — certified by previous barrier
        const unsigned short* Ar = &As[sl][0];
        const unsigned short* Br = &Bs[sl][0];
        bf16x8 af[8], bf[4];
        #pragma unroll
        for (int nf = 0; nf < 4; ++nf) bf[nf] = *(const bf16x8*)(Br + boff[nf]);
        #pragma unroll
        for (int mf = 0; mf < 8; ++mf) af[mf] = *(const bf16x8*)(Ar + aoff[mf]);

        // 2. stage tile t+3; certify tile t+1
        if (t + 3 < nkt) {
            stage((t + 3) & 3, t + 3);
            asm volatile("s_waitcnt vmcnt(8)" ::: "memory");
        } else if (t + 3 == nkt) {
            asm volatile("s_waitcnt vmcnt(4)" ::: "memory");
        } else {
            asm volatile("s_waitcnt vmcnt(0)" ::: "memory");
        }
        // 3. single barrier: publish certification + R/W ordering
        __builtin_amdgcn_s_barrier();
        asm volatile("" ::: "memory");

        // 4. MFMA (compiler lgkmcnt waits on af/bf)
        __builtin_amdgcn_s_setprio(1);
        #pragma unroll
        for (int mf = 0; mf < 8; ++mf)
            #pragma unroll
            for (int nf = 0; nf < 4; ++nf)
                acc[mf][nf] = __builtin_amdgcn_mfma_f32_16x16x32_bf16(af[mf], bf[nf], acc[mf][nf], 0, 0, 0);
        __builtin_amdgcn_s_setprio(0);
    }

    #pragma unroll
    for (int mf = 0; mf < 8; ++mf) {
        #pragma unroll
        for (int nf = 0; nf < 4; ++nf) {
            const int gcol = bn * 256 + wn * 64 + nf * 16 + lr;
            #pragma unroll
            for (int r = 0; r < 4; ++r) {
                const int grow = bm * 256 + wm * 128 + mf * 16 + hk * 4 + r;
                if (MODE == 0) {
                    const int which = gcol >> 10;              // 0=Q 1=K 2=V
                    const int col = gcol & 1023;
                    const float* bp = (which == 0) ? bias0 : (which == 1) ? bias1 : bias2;
                    const float v = acc[mf][nf][r] + bp[col];
                    const int b_ = grow >> 10, s_ = grow & 1023, h_ = col >> 6, d_ = col & 63;
                    outH[(size_t)which * (ROWS * 1024) +
                         (size_t)(b_ * NHEADS + h_) * 65536 + s_ * 64 + d_] = f2bf(v);
                } else {
                    const float v = acc[mf][nf][r] + bias0[gcol];
                    const float t3 = fmaf(0.044715f * v * v, v, v);
                    const float e  = __builtin_amdgcn_exp2f(-2.3022086f * t3);
                    const float ge = v * __builtin_amdgcn_rcpf(1.0f + e);
                    outH[(size_t)grow * N + gcol] = f2bf(ge);
                }
            }
        }
    }
}

// ---------------- flash attention: q-tile 256 (R18-validated) ----------------
__global__ __launch_bounds__(256) void attn_kernel(const unsigned short* __restrict__ q,
    const unsigned short* __restrict__ k, const unsigned short* __restrict__ vT,
    unsigned short* __restrict__ out)
{
    __shared__ __align__(16) unsigned short Ks[2][4096];   // [64 kv][64 d], swizzled
    __shared__ __align__(16) unsigned short Vs[2][4096];   // [64 d][64 kv'], swizzled
    const int tid = threadIdx.x, lane = tid & 63, w = tid >> 6;
    const int bh = blockIdx.y;
    const int q0 = blockIdx.x * 256;
    const size_t headBase = (size_t)bh * (SEQ * HD);   // 65536

    const int qr = lane & 15;
    bf16x8 qf[4][2];
    #pragma unroll
    for (int g = 0; g < 4; ++g) {
        const unsigned short* qp = q + headBase
            + (size_t)(q0 + w * 64 + g * 16 + qr) * HD + (lane >> 4) * 8;
        qf[g][0] = *(const bf16x8*)(qp);
        qf[g][1] = *(const bf16x8*)(qp + 32);
    }

    float lacc[4] = {0.f, 0.f, 0.f, 0.f};
    f32x4 oacc[4][4] = {};

    const int srow = tid >> 3;                          // 0..31
    const int swz  = ((tid & 7) ^ (srow & 7)) * 8;      // pre-swizzled global chunk
    const int pc   = (lane >> 4) ^ (lane & 7);          // physical chunk for swizzled reads

    auto stage = [&](int buf, int kt) {
        #pragma unroll
        for (int s = 0; s < 2; ++s) {
            const unsigned short* gk = k  + headBase + (size_t)(kt + s * 32 + srow) * HD + swz;
            const unsigned short* gv = vT + headBase + (size_t)(s * 32 + srow) * SEQ + kt + swz;
            __builtin_amdgcn_global_load_lds((__attribute__((address_space(1))) void*)gk,
                (__attribute__((address_space(3))) void*)(&Ks[buf][s * 2048 + w * 512]), 16, 0, 0);
            __builtin_amdgcn_global_load_lds((__attribute__((address_space(1))) void*)gv,
                (__attribute__((address_space(3))) void*)(&Vs[buf][s * 2048 + w * 512]), 16, 0, 0);
        }
    };

    stage(0, 0);
    __syncthreads();

    const float C1 = 0.125f * 1.44269504f;
    const float C2 = -4.0f * 1.44269504f;

    for (int t = 0; t < 16; ++t) {
        const int cur = t & 1;
        if (t < 15) stage(cur ^ 1, (t + 1) * 64);

        const unsigned short* KB = &Ks[cur][0];
        const unsigned short* VB = &Vs[cur][0];

        #pragma unroll
        for (int g = 0; g < 4; ++g) {
            f32x4 s4[4] = {};
            __builtin_amdgcn_s_setprio(1);
            #pragma unroll
            for (int ni = 0; ni < 4; ++ni) {
                const unsigned short* pk = KB + (ni * 16 + qr) * 64;
                s4[ni] = __builtin_amdgcn_mfma_f32_16x16x32_bf16(*(const bf16x8*)(pk + pc * 8),       qf[g][0], s4[ni], 0, 0, 0);
                s4[ni] = __builtin_amdgcn_mfma_f32_16x16x32_bf16(*(const bf16x8*)(pk + (pc ^ 4) * 8), qf[g][1], s4[ni], 0, 0, 0);
            }
            __builtin_amdgcn_s_setprio(0);

            unsigned U[4][2];
            float ls = 0.f;
            #pragma unroll
            for (int ni = 0; ni < 4; ++ni) {
                const float p0 = __builtin_amdgcn_exp2f(fmaf(s4[ni][0], C1, C2));
                const float p1 = __builtin_amdgcn_exp2f(fmaf(s4[ni][1], C1, C2));
                const float p2 = __builtin_amdgcn_exp2f(fmaf(s4[ni][2], C1, C2));
                const float p3 = __builtin_amdgcn_exp2f(fmaf(s4[ni][3], C1, C2));
                ls += (p0 + p1) + (p2 + p3);
                asm("v_cvt_pk_bf16_f32 %0, %1, %2" : "=v"(U[ni][0]) : "v"(p0), "v"(p1));
                asm("v_cvt_pk_bf16_f32 %0, %1, %2" : "=v"(U[ni][1]) : "v"(p2), "v"(p3));
            }
            lacc[g] += ls;

            union { unsigned u[4]; bf16x8 v; } W0, W1;
            W0.u[0] = U[0][0]; W0.u[1] = U[0][1]; W0.u[2] = U[1][0]; W0.u[3] = U[1][1];
            W1.u[0] = U[2][0]; W1.u[1] = U[2][1]; W1.u[2] = U[3][0]; W1.u[3] = U[3][1];

            __builtin_amdgcn_s_setprio(1);
            #pragma unroll
            for (int nd = 0; nd < 4; ++nd) {
                const unsigned short* pv = VB + (nd * 16 + qr) * 64;
                oacc[g][nd] = __builtin_amdgcn_mfma_f32_16x16x32_bf16(*(const bf16x8*)(pv + pc * 8),       W0.v, oacc[g][nd], 0, 0, 0);
                oacc[g][nd] = __builtin_amdgcn_mfma_f32_16x16x32_bf16(*(const bf16x8*)(pv + (pc ^ 4) * 8), W1.v, oacc[g][nd], 0, 0, 0);
            }
            __builtin_amdgcn_s_setprio(0);
        }

        __syncthreads();
    }

    const int b_ = bh >> 4, h_ = bh & 15;
    const int hh = (lane >> 4) * 4;
    #pragma unroll
    for (int g = 0; g < 4; ++g) {
        float l = lacc[g];
        l += __shfl_xor(l, 16);
        l += __shfl_xor(l, 32);
        const float inv = 1.0f / l;
        const int s_ = q0 + w * 64 + g * 16 + qr;
        #pragma unroll
        for (int nd = 0; nd < 4; ++nd) {
            ushort4 o;
            o.x = f2bf(oacc[g][nd][0] * inv);
            o.y = f2bf(oacc[g][nd][1] * inv);
            o.z = f2bf(oacc[g][nd][2] * inv);
            o.w = f2bf(oacc[g][nd][3] * inv);
            *(ushort4*)(out + (size_t)(b_ * SEQ + s_) * H_DIM + h_ * 64 + nd * 16 + hh) = o;
        }
    }
}

extern "C" void kernel_launch(void* const* d_in, const int* in_sizes, int n_in,
                              void* d_out, int out_size, void* d_ws, size_t ws_size,
                              hipStream_t stream)
{
    const float* x    = (const float*)d_in[0];
    const float* ln1g = (const float*)d_in[1];
    const float* ln1b = (const float*)d_in[2];
    const float* Wq   = (const float*)d_in[3];
    const float* bq   = (const float*)d_in[4];
    const float* Wk   = (const float*)d_in[5];
    const float* bk   = (const float*)d_in[6];
    const float* Wv   = (const float*)d_in[7];
    const float* bv   = (const float*)d_in[8];
    const float* Wo   = (const float*)d_in[9];
    const float* bo   = (const float*)d_in[10];
    const float* ln2g = (const float*)d_in[11];
    const float* ln2b = (const float*)d_in[12];
    const float* W1   = (const float*)d_in[13];
    const float* b1   = (const float*)d_in[14];
    const float* W2   = (const float*)d_in[15];
    const float* b2   = (const float*)d_in[16];
    float* out = (float*)d_out;

    char* ws = (char*)d_ws;
    const size_t MB = 1024 * 1024;
    unsigned short* h1  = (unsigned short*)(ws);
    unsigned short* qb  = (unsigned short*)(ws + 16 * MB);
    unsigned short* kb  = (unsigned short*)(ws + 32 * MB);
    unsigned short* vb  = (unsigned short*)(ws + 48 * MB);
    unsigned short* vTb = (unsigned short*)(ws + 64 * MB);
    unsigned short* mlp = (unsigned short*)(ws + 16 * MB);
    unsigned short* ao  = h1;
    unsigned short* WqT = (unsigned short*)(ws + 80 * MB);   // contiguous QKV weights
    unsigned short* WkT = (unsigned short*)(ws + 82 * MB);
    unsigned short* WvT = (unsigned short*)(ws + 84 * MB);
    unsigned short* WoT = (unsigned short*)(ws + 86 * MB);
    unsigned short* W1T = (unsigned short*)(ws + 88 * MB);   // 8MB
    unsigned short* W2T = (unsigned short*)(ws + 96 * MB);   // 8MB

    transpose_all<<<12288, dim3(32, 8), 0, stream>>>(Wq, Wk, Wv, Wo, W1, W2,
                                                     WqT, WkT, WvT, WoT, W1T, W2T);

    ln_kernel<<<ROWS, 256, 0, stream>>>(x, ln1g, ln1b, h1);

    // fused QKV: 4-slot K-phased 256x256 -> 32x12 = 384 blocks
    gemm_kp4<0><<<384, 512, 0, stream>>>(h1, WqT, bq, bk, bv, qb, 3072, 1024, 12);

    transpose_v<<<dim3(2, 32, 128), dim3(32, 8), 0, stream>>>(vb, vTb);

    attn_kernel<<<dim3(4, 128), 256, 0, stream>>>(qb, kb, vTb, ao);

    // O-proj + residual: 64x8 = 512 blocks (BK=128 gemm_dp)
    gemm_dp<2><<<512, 256, 0, stream>>>(ao, WoT, bo, bo, bo, x, out, nullptr, 1024, 1024, 8);

    ln_kernel<<<ROWS, 256, 0, stream>>>(out, ln2g, ln2b, h1);

    // MLP1 + gelu: 4-slot K-phased 256x256 -> 32x16 = 512 blocks
    gemm_kp4<3><<<512, 512, 0, stream>>>(h1, W1T, b1, b1, b1, mlp, 4096, 1024, 16);
    // MLP2 + residual: BK=128 gemm_dp -> 64x8 = 512 blocks
    gemm_dp<2><<<512, 256, 0, stream>>>(mlp, W2T, b2, b2, b2, out, out, nullptr, 1024, 4096, 8);
}

// Round 20
// 344.148 us; speedup vs baseline: 1.0080x; 1.0080x over previous
//
#include <hip/hip_runtime.h>

#define H_DIM 1024
#define NHEADS 16
#define HD 64
#define SEQ 1024
#define BATCH 8
#define ROWS (BATCH*SEQ)   // 8192
#define MLPD 4096

typedef __bf16 bf16x8 __attribute__((ext_vector_type(8)));
typedef float f32x4 __attribute__((ext_vector_type(4)));

__device__ __forceinline__ unsigned short f2bf(float f) {
    unsigned u = __float_as_uint(f);
    unsigned r = u + 0x7FFFu + ((u >> 16) & 1u);   // RNE
    return (unsigned short)(r >> 16);
}

// ------- fused weight transpose: all 6 weights fp32(K,N) -> bf16(N,K) -------
__global__ void transpose_all(const float* __restrict__ Wq, const float* __restrict__ Wk,
                              const float* __restrict__ Wv, const float* __restrict__ Wo,
                              const float* __restrict__ W1, const float* __restrict__ W2,
                              unsigned short* __restrict__ WqT, unsigned short* __restrict__ WkT,
                              unsigned short* __restrict__ WvT, unsigned short* __restrict__ WoT,
                              unsigned short* __restrict__ W1T, unsigned short* __restrict__ W2T)
{
    __shared__ float tile[32][33];
    const int id = blockIdx.x;
    const float* in; unsigned short* outp; int K, N, t;
    if (id < 4096) {
        const int wsel = id >> 10; t = id & 1023;
        in   = (wsel == 0) ? Wq  : (wsel == 1) ? Wk  : (wsel == 2) ? Wv  : Wo;
        outp = (wsel == 0) ? WqT : (wsel == 1) ? WkT : (wsel == 2) ? WvT : WoT;
        K = 1024; N = 1024;
    } else if (id < 8192) {
        t = id - 4096; in = W1; outp = W1T; K = 1024; N = 4096;
    } else {
        t = id - 8192; in = W2; outp = W2T; K = 4096; N = 1024;
    }
    const int ntx = N >> 5;
    const int n0 = (t % ntx) * 32, k0 = (t / ntx) * 32;
    const int tx = threadIdx.x, ty = threadIdx.y;      // (32,8)
    #pragma unroll
    for (int i = ty; i < 32; i += 8)
        tile[i][tx] = in[(size_t)(k0 + i) * N + n0 + tx];
    __syncthreads();
    #pragma unroll
    for (int i = ty; i < 32; i += 8)
        outp[(size_t)(n0 + i) * K + k0 + tx] = f2bf(tile[tx][i]);
}

// ---- per-head bf16 transpose with kv-permuted columns (R6-validated) ----
__global__ void transpose_v(const unsigned short* __restrict__ in,
                            unsigned short* __restrict__ out)
{
    __shared__ unsigned short tile[32][33];
    const size_t base = (size_t)blockIdx.z * (SEQ * HD);
    const int d0 = blockIdx.x * 32, s0 = blockIdx.y * 32;
    const int tx = threadIdx.x, ty = threadIdx.y;      // (32,8)
    #pragma unroll
    for (int i = ty; i < 32; i += 8)
        tile[i][tx] = in[base + (size_t)(s0 + i) * HD + d0 + tx];
    __syncthreads();
    const int fx = ((tx & 12) << 1) | ((tx & 16) >> 2) | (tx & 3);   // kv -> kv'
    #pragma unroll
    for (int i = ty; i < 32; i += 8)
        out[base + (size_t)(d0 + i) * SEQ + s0 + fx] = tile[tx][i];
}

// ---------------- layernorm fp32 -> bf16, one block per row ----------------
__global__ __launch_bounds__(256) void ln_kernel(const float* __restrict__ x,
    const float* __restrict__ g, const float* __restrict__ b,
    unsigned short* __restrict__ out)
{
    __shared__ float red[4];
    const int row = blockIdx.x;
    const int tid = threadIdx.x;
    const float4 v = *(const float4*)(x + (size_t)row * H_DIM + tid * 4);
    float s = v.x + v.y + v.z + v.w;
    #pragma unroll
    for (int off = 32; off >= 1; off >>= 1) s += __shfl_xor(s, off);
    if ((tid & 63) == 0) red[tid >> 6] = s;
    __syncthreads();
    const float mu = (red[0] + red[1] + red[2] + red[3]) * (1.0f / H_DIM);
    __syncthreads();
    const float dx = v.x - mu, dy = v.y - mu, dz = v.z - mu, dw = v.w - mu;
    float q = dx * dx + dy * dy + dz * dz + dw * dw;
    #pragma unroll
    for (int off = 32; off >= 1; off >>= 1) q += __shfl_xor(q, off);
    if ((tid & 63) == 0) red[tid >> 6] = q;
    __syncthreads();
    const float var = (red[0] + red[1] + red[2] + red[3]) * (1.0f / H_DIM);
    const float rstd = rsqrtf(var + 1e-6f);
    const float4 gv = *(const float4*)(g + tid * 4);
    const float4 bv = *(const float4*)(b + tid * 4);
    ushort4 o;
    o.x = f2bf(dx * rstd * gv.x + bv.x);
    o.y = f2bf(dy * rstd * gv.y + bv.y);
    o.z = f2bf(dz * rstd * gv.z + bv.z);
    o.w = f2bf(dw * rstd * gv.w + bv.w);
    *(ushort4*)(out + (size_t)row * H_DIM + tid * 4) = o;
}

// ---------------- bf16 GEMM: 128x128, BK=128, 4 waves, single-buffer --------
// MODE 2: f32 out = resid + C
template<int MODE>
__global__ __launch_bounds__(256) void gemm_dp(
    const unsigned short* __restrict__ A, const unsigned short* __restrict__ Bt,
    const float* __restrict__ bias0, const float* __restrict__ bias1,
    const float* __restrict__ bias2, const float* resid,
    float* outF, unsigned short* __restrict__ outH,
    int N, int K, int gn)
{
    __shared__ __align__(16) unsigned short As[128 * 128];   // 32 KB
    __shared__ __align__(16) unsigned short Bs[128 * 128];   // 32 KB

    const int tid = threadIdx.x, lane = tid & 63;
    const int w = tid >> 6;
    const int wm = w >> 1, wn = w & 1;  // 2x2 wave grid, 64x64 per wave

    const int nwg = gridDim.x;
    const int swzb = (blockIdx.x & 7) * (nwg >> 3) + (blockIdx.x >> 3);
    const int bm = swzb / gn, bn = swzb % gn;

    const int srow = tid >> 4;                        // 0..15 (row within round)
    const int sc = (tid & 15) ^ (srow & 7);           // pre-swizzled global chunk
    const unsigned short* Abase = A  + (size_t)(bm * 128) * K;
    const unsigned short* Bbase = Bt + (size_t)(bn * 128) * K;

    auto stage = [&](int kt) {
        const size_t kofs = (size_t)kt * 128 + sc * 8;
        #pragma unroll
        for (int q = 0; q < 8; ++q)
            __builtin_amdgcn_global_load_lds(
                (__attribute__((address_space(1))) void*)(Abase + (size_t)(q * 16 + srow) * K + kofs),
                (__attribute__((address_space(3))) void*)(&As[q * 2048 + tid * 8]), 16, 0, 0);
        #pragma unroll
        for (int q = 0; q < 8; ++q)
            __builtin_amdgcn_global_load_lds(
                (__attribute__((address_space(1))) void*)(Bbase + (size_t)(q * 16 + srow) * K + kofs),
                (__attribute__((address_space(3))) void*)(&Bs[q * 2048 + tid * 8]), 16, 0, 0);
    };

    const int lr = lane & 15, hk = lane >> 4, sx = lr & 7;
    const int arow = (wm * 64 + lr) * 128;
    const int brow = (wn * 64 + lr) * 128;

    f32x4 acc[4][4] = {};
    const int nkt = K >> 7;

    for (int t = 0; t < nkt; ++t) {
        stage(t);
        __syncthreads();                 // drains vmcnt(0): stage(t) landed

        const unsigned short* Ab = &As[arow];
        const unsigned short* Bb = &Bs[brow];

        #pragma unroll
        for (int ks = 0; ks < 4; ++ks) {
            const int px = ((ks * 4 + hk) ^ sx) * 8;
            bf16x8 a[4], b[4];
            #pragma unroll
            for (int i = 0; i < 4; ++i) { b[i] = *(const bf16x8*)(Bb + i * 2048 + px);
                                          a[i] = *(const bf16x8*)(Ab + i * 2048 + px); }
            __builtin_amdgcn_s_setprio(1);
            #pragma unroll
            for (int mi = 0; mi < 4; ++mi)
                #pragma unroll
                for (int ni = 0; ni < 4; ++ni)
                    acc[mi][ni] = __builtin_amdgcn_mfma_f32_16x16x32_bf16(a[mi], b[ni], acc[mi][ni], 0, 0, 0);
            __builtin_amdgcn_s_setprio(0);
        }
        __syncthreads();                 // all reads done before next overwrite
    }

    #pragma unroll
    for (int mi = 0; mi < 4; ++mi) {
        #pragma unroll
        for (int ni = 0; ni < 4; ++ni) {
            const int gcol = bn * 128 + wn * 64 + ni * 16 + lr;
            #pragma unroll
            for (int r = 0; r < 4; ++r) {
                const int grow = bm * 128 + wm * 64 + mi * 16 + hk * 4 + r;
                if (MODE == 2) {
                    const float v = acc[mi][ni][r] + bias0[gcol];
                    const size_t idx = (size_t)grow * N + gcol;
                    outF[idx] = resid[idx] + v;
                }
            }
        }
    }
}

// ---------------- K-phased deep-pipeline GEMM (R13/R18-validated, BN=256) ----
// MODE 0: fused QKV scatter   MODE 3: gelu
template<int MODE, int BN>
__global__ __launch_bounds__(512) void gemm_kp(
    const unsigned short* __restrict__ A, const unsigned short* __restrict__ Bt,
    const float* __restrict__ bias0, const float* __restrict__ bias1,
    const float* __restrict__ bias2, const float* resid,
    float* outF, unsigned short* __restrict__ outH,
    int N, int K, int gn)
{
    constexpr int WN = (BN == 256) ? 4 : 2;
    constexpr int WM = 8 / WN;
    constexpr int RM = 256 / WM;
    constexpr int RN = BN / WN;
    constexpr int MR = RM / 16;
    constexpr int NR = RN / 16;
    constexpr int BJ = BN / 128;

    __shared__ __align__(16) unsigned short As[2][2][8192];
    __shared__ __align__(16) unsigned short Bs[2][2][BN * 32];

    const int tid = threadIdx.x, lane = tid & 63;
    const int w = tid >> 6;
    const int wm = w / WN, wn = w % WN;

    const int nwg = gridDim.x;
    const int swzb = (blockIdx.x & 7) * (nwg >> 3) + (blockIdx.x >> 3);
    const int bm = swzb / gn, bn = swzb % gn;

    const unsigned short* Abase = A  + (size_t)(bm * 256) * K;
    const unsigned short* Bbase = Bt + (size_t)(bn * BN) * K;

    int asrow[2], asoff[2];
    #pragma unroll
    for (int j = 0; j < 2; ++j) {
        const int slot = j * 512 + tid;
        asrow[j] = slot >> 2;
        asoff[j] = ((slot & 3) ^ ((asrow[j] >> 1) & 3)) * 8;
    }
    int bsrow[BJ], bsoff[BJ];
    #pragma unroll
    for (int j = 0; j < BJ; ++j) {
        const int slot = j * 512 + tid;
        bsrow[j] = slot >> 2;
        bsoff[j] = ((slot & 3) ^ ((bsrow[j] >> 1) & 3)) * 8;
    }

    auto stageKH = [&](int buf, int kt, int s) {
        #pragma unroll
        for (int j = 0; j < 2; ++j)
            __builtin_amdgcn_global_load_lds(
                (__attribute__((address_space(1))) void*)(Abase + (size_t)asrow[j] * K + (size_t)kt * 64 + s * 32 + asoff[j]),
                (__attribute__((address_space(3))) void*)(&As[buf][s][(j * 512 + tid) * 8]), 16, 0, 0);
        #pragma unroll
        for (int j = 0; j < BJ; ++j)
            __builtin_amdgcn_global_load_lds(
                (__attribute__((address_space(1))) void*)(Bbase + (size_t)bsrow[j] * K + (size_t)kt * 64 + s * 32 + bsoff[j]),
                (__attribute__((address_space(3))) void*)(&Bs[buf][s][(j * 512 + tid) * 8]), 16, 0, 0);
    };

    const int lr = lane & 15, hk = lane >> 4;
    int aoff[MR], boff[NR];
    #pragma unroll
    for (int mf = 0; mf < MR; ++mf) {
        const int R = wm * RM + mf * 16 + lr;
        aoff[mf] = R * 32 + ((hk ^ ((R >> 1) & 3)) * 8);
    }
    #pragma unroll
    for (int nf = 0; nf < NR; ++nf) {
        const int R = wn * RN + nf * 16 + lr;
        boff[nf] = R * 32 + ((hk ^ ((R >> 1) & 3)) * 8);
    }

    f32x4 acc[MR][NR] = {};
    const int nkt = K >> 6;

    stageKH(0, 0, 0);
    stageKH(0, 0, 1);
    if constexpr (BJ == 2) asm volatile("s_waitcnt vmcnt(4)" ::: "memory");
    else                   asm volatile("s_waitcnt vmcnt(3)" ::: "memory");
    __builtin_amdgcn_s_barrier();
    asm volatile("" ::: "memory");

    for (int t = 0; t < nkt; ++t) {
        const int buf = t & 1;
        #pragma unroll
        for (int s = 0; s < 2; ++s) {
            const unsigned short* Ar = &As[buf][s][0];
            const unsigned short* Br = &Bs[buf][s][0];
            bf16x8 af[MR], bf[NR];
            #pragma unroll
            for (int nf = 0; nf < NR; ++nf) bf[nf] = *(const bf16x8*)(Br + boff[nf]);
            #pragma unroll
            for (int mf = 0; mf < MR; ++mf) af[mf] = *(const bf16x8*)(Ar + aoff[mf]);

            if (t + 1 < nkt) {
                stageKH(buf ^ 1, t + 1, s);
                if constexpr (BJ == 2) asm volatile("s_waitcnt vmcnt(4)" ::: "memory");
                else                   asm volatile("s_waitcnt vmcnt(3)" ::: "memory");
            } else {
                asm volatile("s_waitcnt vmcnt(0)" ::: "memory");
            }
            __builtin_amdgcn_s_barrier();
            asm volatile("" ::: "memory");

            __builtin_amdgcn_s_setprio(1);
            #pragma unroll
            for (int mf = 0; mf < MR; ++mf)
                #pragma unroll
                for (int nf = 0; nf < NR; ++nf)
                    acc[mf][nf] = __builtin_amdgcn_mfma_f32_16x16x32_bf16(af[mf], bf[nf], acc[mf][nf], 0, 0, 0);
            __builtin_amdgcn_s_setprio(0);
        }
    }

    #pragma unroll
    for (int mf = 0; mf < MR; ++mf) {
        #pragma unroll
        for (int nf = 0; nf < NR; ++nf) {
            const int gcol = bn * BN + wn * RN + nf * 16 + lr;
            #pragma unroll
            for (int r = 0; r < 4; ++r) {
                const int grow = bm * 256 + wm * RM + mf * 16 + hk * 4 + r;
                if (MODE == 0) {
                    const int which = gcol >> 10;              // 0=Q 1=K 2=V
                    const int col = gcol & 1023;
                    const float* bp = (which == 0) ? bias0 : (which == 1) ? bias1 : bias2;
                    const float v = acc[mf][nf][r] + bp[col];
                    const int b_ = grow >> 10, s_ = grow & 1023, h_ = col >> 6, d_ = col & 63;
                    outH[(size_t)which * (ROWS * 1024) +
                         (size_t)(b_ * NHEADS + h_) * 65536 + s_ * 64 + d_] = f2bf(v);
                } else {
                    const float v = acc[mf][nf][r] + bias0[gcol];
                    const float t3 = fmaf(0.044715f * v * v, v, v);
                    const float e  = __builtin_amdgcn_exp2f(-2.3022086f * t3);
                    const float ge = v * __builtin_amdgcn_rcpf(1.0f + e);
                    outH[(size_t)grow * N + gcol] = f2bf(ge);
                }
            }
        }
    }
}

// ---------------- flash attention: q-tile 256 + XCD swizzle (T1) -------------
// 1-D grid 512 = 128 heads x 4 q-blocks; bijective swizzle puts all 4 q-blocks
// of a head on ONE XCD -> its 256 KB K/V fetched once per XCD L2, not 4x.
__global__ __launch_bounds__(256) void attn_kernel(const unsigned short* __restrict__ q,
    const unsigned short* __restrict__ k, const unsigned short* __restrict__ vT,
    unsigned short* __restrict__ out)
{
    __shared__ __align__(16) unsigned short Ks[2][4096];   // [64 kv][64 d], swizzled
    __shared__ __align__(16) unsigned short Vs[2][4096];   // [64 d][64 kv'], swizzled
    const int tid = threadIdx.x, lane = tid & 63, w = tid >> 6;
    const int flat = blockIdx.x;                       // 0..511
    const int swzB = (flat & 7) * 64 + (flat >> 3);    // bijective (512 % 8 == 0)
    const int bh = swzB >> 2;                          // head
    const int q0 = (swzB & 3) * 256;                   // q-block within head
    const size_t headBase = (size_t)bh * (SEQ * HD);   // 65536

    const int qr = lane & 15;
    bf16x8 qf[4][2];
    #pragma unroll
    for (int g = 0; g < 4; ++g) {
        const unsigned short* qp = q + headBase
            + (size_t)(q0 + w * 64 + g * 16 + qr) * HD + (lane >> 4) * 8;
        qf[g][0] = *(const bf16x8*)(qp);
        qf[g][1] = *(const bf16x8*)(qp + 32);
    }

    float lacc[4] = {0.f, 0.f, 0.f, 0.f};
    f32x4 oacc[4][4] = {};

    const int srow = tid >> 3;                          // 0..31
    const int swz  = ((tid & 7) ^ (srow & 7)) * 8;      // pre-swizzled global chunk
    const int pc   = (lane >> 4) ^ (lane & 7);          // physical chunk for swizzled reads

    auto stage = [&](int buf, int kt) {
        #pragma unroll
        for (int s = 0; s < 2; ++s) {
            const unsigned short* gk = k  + headBase + (size_t)(kt + s * 32 + srow) * HD + swz;
            const unsigned short* gv = vT + headBase + (size_t)(s * 32 + srow) * SEQ + kt + swz;
            __builtin_amdgcn_global_load_lds((__attribute__((address_space(1))) void*)gk,
                (__attribute__((address_space(3))) void*)(&Ks[buf][s * 2048 + w * 512]), 16, 0, 0);
            __builtin_amdgcn_global_load_lds((__attribute__((address_space(1))) void*)gv,
                (__attribute__((address_space(3))) void*)(&Vs[buf][s * 2048 + w * 512]), 16, 0, 0);
        }
    };

    stage(0, 0);
    __syncthreads();

    const float C1 = 0.125f * 1.44269504f;
    const float C2 = -4.0f * 1.44269504f;

    for (int t = 0; t < 16; ++t) {
        const int cur = t & 1;
        if (t < 15) stage(cur ^ 1, (t + 1) * 64);

        const unsigned short* KB = &Ks[cur][0];
        const unsigned short* VB = &Vs[cur][0];

        #pragma unroll
        for (int g = 0; g < 4; ++g) {
            f32x4 s4[4] = {};
            __builtin_amdgcn_s_setprio(1);
            #pragma unroll
            for (int ni = 0; ni < 4; ++ni) {
                const unsigned short* pk = KB + (ni * 16 + qr) * 64;
                s4[ni] = __builtin_amdgcn_mfma_f32_16x16x32_bf16(*(const bf16x8*)(pk + pc * 8),       qf[g][0], s4[ni], 0, 0, 0);
                s4[ni] = __builtin_amdgcn_mfma_f32_16x16x32_bf16(*(const bf16x8*)(pk + (pc ^ 4) * 8), qf[g][1], s4[ni], 0, 0, 0);
            }
            __builtin_amdgcn_s_setprio(0);

            unsigned U[4][2];
            float ls = 0.f;
            #pragma unroll
            for (int ni = 0; ni < 4; ++ni) {
                const float p0 = __builtin_amdgcn_exp2f(fmaf(s4[ni][0], C1, C2));
                const float p1 = __builtin_amdgcn_exp2f(fmaf(s4[ni][1], C1, C2));
                const float p2 = __builtin_amdgcn_exp2f(fmaf(s4[ni][2], C1, C2));
                const float p3 = __builtin_amdgcn_exp2f(fmaf(s4[ni][3], C1, C2));
                ls += (p0 + p1) + (p2 + p3);
                asm("v_cvt_pk_bf16_f32 %0, %1, %2" : "=v"(U[ni][0]) : "v"(p0), "v"(p1));
                asm("v_cvt_pk_bf16_f32 %0, %1, %2" : "=v"(U[ni][1]) : "v"(p2), "v"(p3));
            }
            lacc[g] += ls;

            union { unsigned u[4]; bf16x8 v; } W0, W1;
            W0.u[0] = U[0][0]; W0.u[1] = U[0][1]; W0.u[2] = U[1][0]; W0.u[3] = U[1][1];
            W1.u[0] = U[2][0]; W1.u[1] = U[2][1]; W1.u[2] = U[3][0]; W1.u[3] = U[3][1];

            __builtin_amdgcn_s_setprio(1);
            #pragma unroll
            for (int nd = 0; nd < 4; ++nd) {
                const unsigned short* pv = VB + (nd * 16 + qr) * 64;
                oacc[g][nd] = __builtin_amdgcn_mfma_f32_16x16x32_bf16(*(const bf16x8*)(pv + pc * 8),       W0.v, oacc[g][nd], 0, 0, 0);
                oacc[g][nd] = __builtin_amdgcn_mfma_f32_16x16x32_bf16(*(const bf16x8*)(pv + (pc ^ 4) * 8), W1.v, oacc[g][nd], 0, 0, 0);
            }
            __builtin_amdgcn_s_setprio(0);
        }

        __syncthreads();
    }

    const int b_ = bh >> 4, h_ = bh & 15;
    const int hh = (lane >> 4) * 4;
    #pragma unroll
    for (int g = 0; g < 4; ++g) {
        float l = lacc[g];
        l += __shfl_xor(l, 16);
        l += __shfl_xor(l, 32);
        const float inv = 1.0f / l;
        const int s_ = q0 + w * 64 + g * 16 + qr;
        #pragma unroll
        for (int nd = 0; nd < 4; ++nd) {
            ushort4 o;
            o.x = f2bf(oacc[g][nd][0] * inv);
            o.y = f2bf(oacc[g][nd][1] * inv);
            o.z = f2bf(oacc[g][nd][2] * inv);
            o.w = f2bf(oacc[g][nd][3] * inv);
            *(ushort4*)(out + (size_t)(b_ * SEQ + s_) * H_DIM + h_ * 64 + nd * 16 + hh) = o;
        }
    }
}

extern "C" void kernel_launch(void* const* d_in, const int* in_sizes, int n_in,
                              void* d_out, int out_size, void* d_ws, size_t ws_size,
                              hipStream_t stream)
{
    const float* x    = (const float*)d_in[0];
    const float* ln1g = (const float*)d_in[1];
    const float* ln1b = (const float*)d_in[2];
    const float* Wq   = (const float*)d_in[3];
    const float* bq   = (const float*)d_in[4];
    const float* Wk   = (const float*)d_in[5];
    const float* bk   = (const float*)d_in[6];
    const float* Wv   = (const float*)d_in[7];
    const float* bv   = (const float*)d_in[8];
    const float* Wo   = (const float*)d_in[9];
    const float* bo   = (const float*)d_in[10];
    const float* ln2g = (const float*)d_in[11];
    const float* ln2b = (const float*)d_in[12];
    const float* W1   = (const float*)d_in[13];
    const float* b1   = (const float*)d_in[14];
    const float* W2   = (const float*)d_in[15];
    const float* b2   = (const float*)d_in[16];
    float* out = (float*)d_out;

    char* ws = (char*)d_ws;
    const size_t MB = 1024 * 1024;
    unsigned short* h1  = (unsigned short*)(ws);
    unsigned short* qb  = (unsigned short*)(ws + 16 * MB);
    unsigned short* kb  = (unsigned short*)(ws + 32 * MB);
    unsigned short* vb  = (unsigned short*)(ws + 48 * MB);
    unsigned short* vTb = (unsigned short*)(ws + 64 * MB);
    unsigned short* mlp = (unsigned short*)(ws + 16 * MB);
    unsigned short* ao  = h1;
    unsigned short* WqT = (unsigned short*)(ws + 80 * MB);   // contiguous QKV weights
    unsigned short* WkT = (unsigned short*)(ws + 82 * MB);
    unsigned short* WvT = (unsigned short*)(ws + 84 * MB);
    unsigned short* WoT = (unsigned short*)(ws + 86 * MB);
    unsigned short* W1T = (unsigned short*)(ws + 88 * MB);   // 8MB
    unsigned short* W2T = (unsigned short*)(ws + 96 * MB);   // 8MB

    transpose_all<<<12288, dim3(32, 8), 0, stream>>>(Wq, Wk, Wv, Wo, W1, W2,
                                                     WqT, WkT, WvT, WoT, W1T, W2T);

    ln_kernel<<<ROWS, 256, 0, stream>>>(x, ln1g, ln1b, h1);

    // fused QKV: K-phased 256x256 -> 32x12 = 384 blocks (R18 config)
    gemm_kp<0, 256><<<384, 512, 0, stream>>>(h1, WqT, bq, bk, bv, nullptr, nullptr, qb, 3072, 1024, 12);

    transpose_v<<<dim3(2, 32, 128), dim3(32, 8), 0, stream>>>(vb, vTb);

    attn_kernel<<<512, 256, 0, stream>>>(qb, kb, vTb, ao);

    // O-proj + residual: 64x8 = 512 blocks (BK=128 gemm_dp)
    gemm_dp<2><<<512, 256, 0, stream>>>(ao, WoT, bo, bo, bo, x, out, nullptr, 1024, 1024, 8);

    ln_kernel<<<ROWS, 256, 0, stream>>>(out, ln2g, ln2b, h1);

    // MLP1 + gelu: K-phased 256x256 -> 32x16 = 512 blocks (R18 config)
    gemm_kp<3, 256><<<512, 512, 0, stream>>>(h1, W1T, b1, b1, b1, nullptr, nullptr, mlp, 4096, 1024, 16);
    // MLP2 + residual: BK=128 gemm_dp -> 64x8 = 512 blocks
    gemm_dp<2><<<512, 256, 0, stream>>>(mlp, W2T, b2, b2, b2, out, out, nullptr, 1024, 4096, 8);
}